// Round 16
// baseline (1026.487 us; speedup 1.0000x reference)
//
#include <hip/hip_runtime.h>

#define N_NODES 100000
#define NEDGE   1600000
#define NHID    128
#define NCLASS  40

#define AGG_NODES 128
#define COLV_LDS  3072
#define FILL_RANGE  12500   // N_NODES / 8
#define WPREP_TOT   264192  // 6*16384 + 147456 + 18432
#define EPB 2048            // edges per k_bucket block
#define NBB 782             // (NEDGE + EPB - 1) / EPB
#define SUBN 196            // nodes per cnt3/fill3 block (64 * 196 >= 12500)

using bf16x8 = __attribute__((ext_vector_type(8))) short;
using f32x4  = __attribute__((ext_vector_type(4))) float;

__device__ __forceinline__ float bf2f(unsigned short s) {
    unsigned u = ((unsigned)s) << 16; float f; __builtin_memcpy(&f, &u, 4); return f;
}
__device__ __forceinline__ unsigned short f2bf(float f) {
    unsigned u; __builtin_memcpy(&u, &f, 4);
    u = u + 0x7fffu + ((u >> 16) & 1u);          // RNE
    return (unsigned short)(u >> 16);
}

// global -> LDS direct (16B/lane). Dest: wave-uniform base; HW adds lane*16.
__device__ __forceinline__ void gld16(const void* g, void* l) {
    __builtin_amdgcn_global_load_lds(g, l, 16, 0, 0);
}

// ---------------- CSR build: one-pass ballot bucketing ----------------
__global__ __launch_bounds__(256) void k_bucket(const int* __restrict__ ei,
                                                unsigned* __restrict__ pairs,
                                                int* __restrict__ bofs, int* __restrict__ bcnt) {
    __shared__ int wcnt[4][8];
    __shared__ int wbase[4][8];
    __shared__ int sbase[9];
    const int tid = threadIdx.x, lane = tid & 63, w = tid >> 6;
    const int e0 = blockIdx.x * EPB;
    const unsigned long long below = (1ull << lane) - 1ull;

    int dl[8], src[8], sl[8], posw[8];
    int cnt[8] = {0, 0, 0, 0, 0, 0, 0, 0};   // wave-uniform (same ballots all lanes)
    #pragma unroll
    for (int k = 0; k < 8; ++k) {
        int e = e0 + w * 512 + k * 64 + lane;
        bool v = e < NEDGE;
        int d = v ? ei[NEDGE + e] : -1;
        src[k] = v ? ei[e] : 0;
        int slc = v ? d / FILL_RANGE : -1;
        sl[k] = slc;
        dl[k] = v ? d - slc * FILL_RANGE : 0;
        posw[k] = 0;
        #pragma unroll
        for (int s = 0; s < 8; ++s) {
            unsigned long long mask = __ballot(slc == s);
            if (slc == s) posw[k] = cnt[s] + (int)__popcll(mask & below);
            cnt[s] += (int)__popcll(mask);
        }
    }
    if (lane == 0) {
        #pragma unroll
        for (int s = 0; s < 8; ++s) wcnt[w][s] = cnt[s];
    }
    __syncthreads();
    if (tid == 0) {
        int run = 0;
        for (int s = 0; s < 8; ++s) {
            sbase[s] = run;
            for (int w2 = 0; w2 < 4; ++w2) { wbase[w2][s] = run; run += wcnt[w2][s]; }
        }
        sbase[8] = run;
        for (int s = 0; s < 8; ++s) {
            bofs[blockIdx.x * 8 + s] = e0 + sbase[s];
            bcnt[blockIdx.x * 8 + s] = sbase[s + 1] - sbase[s];
        }
    }
    __syncthreads();
    #pragma unroll
    for (int k = 0; k < 8; ++k) {
        if (sl[k] >= 0)
            pairs[e0 + wbase[w][sl[k]] + posw[k]] = ((unsigned)dl[k] << 17) | (unsigned)src[k];
    }
}

// subrange-exclusive count: block = (slice, 196-node subrange). LDS counters only,
// cnt written contiguously -> ZERO global atomics.
__global__ __launch_bounds__(256) void k_cnt3(const unsigned* __restrict__ pairs,
                                              const int* __restrict__ bofs,
                                              const int* __restrict__ bcnt,
                                              int* __restrict__ cnt) {
    __shared__ int lcnt[SUBN];
    const int s = blockIdx.x & 7, sub = blockIdx.x >> 3;
    const int nlo = sub * SUBN;
    const int nhi = (nlo + SUBN < FILL_RANGE) ? nlo + SUBN : FILL_RANGE;
    const int tid = threadIdx.x;
    for (int i = tid; i < SUBN; i += 256) lcnt[i] = 0;
    __syncthreads();
    for (int bb = 0; bb < NBB; ++bb) {
        int beg = bofs[bb * 8 + s], n = bcnt[bb * 8 + s];
        for (int i = tid; i < n; i += 256) {
            int dl = (int)(pairs[beg + i] >> 17);
            if (dl >= nlo && dl < nhi) atomicAdd(&lcnt[dl - nlo], 1);
        }
    }
    __syncthreads();
    int base = s * FILL_RANGE + nlo;
    for (int i = tid; i < nhi - nlo; i += 256) cnt[base + i] = lcnt[i];
}

__global__ void k_scan1(const int* __restrict__ cnt, int* __restrict__ rp, int* __restrict__ bsum) {
    __shared__ int sh[256];
    int t = threadIdx.x, base = blockIdx.x * 1024;
    int v[4]; int s = 0;
    for (int k = 0; k < 4; ++k) { int i = base + t * 4 + k; v[k] = (i < N_NODES) ? cnt[i] : 0; s += v[k]; }
    sh[t] = s; __syncthreads();
    for (int off = 1; off < 256; off <<= 1) {
        int x = (t >= off) ? sh[t - off] : 0;
        __syncthreads();
        sh[t] += x;
        __syncthreads();
    }
    int excl = sh[t] - s;
    for (int k = 0; k < 4; ++k) { int i = base + t * 4 + k; if (i < N_NODES) rp[i] = excl; excl += v[k]; }
    if (t == 255) bsum[blockIdx.x] = sh[255];
}

__global__ void k_scan2(int* __restrict__ bsum, int nb) {
    __shared__ int sh[256];
    int t = threadIdx.x;
    int v = (t < nb) ? bsum[t] : 0;
    sh[t] = v; __syncthreads();
    for (int off = 1; off < 256; off <<= 1) {
        int x = (t >= off) ? sh[t - off] : 0;
        __syncthreads();
        sh[t] += x;
        __syncthreads();
    }
    if (t < nb) bsum[t] = sh[t] - v;   // exclusive block offsets
}

__global__ void k_scan3(int* __restrict__ rp, const int* __restrict__ bsum) {
    int base = blockIdx.x * 1024;
    int off = bsum[blockIdx.x];
    for (int k = 0; k < 4; ++k) {
        int i = base + threadIdx.x * 4 + k;
        if (i < N_NODES) rp[i] += off;
    }
    if (blockIdx.x == 0 && threadIdx.x == 0) rp[N_NODES] = NEDGE;
}

// subrange-exclusive fill: LDS cursors, colv writes land in an exclusive ~12KB window.
__global__ __launch_bounds__(256) void k_fill3(const unsigned* __restrict__ pairs,
                                               const int* __restrict__ bofs,
                                               const int* __restrict__ bcnt,
                                               const int* __restrict__ rp,
                                               int* __restrict__ colv) {
    __shared__ int lcur[SUBN];
    __shared__ int lrp[SUBN];
    const int s = blockIdx.x & 7, sub = blockIdx.x >> 3;
    const int nlo = sub * SUBN;
    const int nhi = (nlo + SUBN < FILL_RANGE) ? nlo + SUBN : FILL_RANGE;
    const int tid = threadIdx.x;
    const int gbase = s * FILL_RANGE + nlo;
    for (int i = tid; i < SUBN; i += 256) {
        lcur[i] = 0;
        lrp[i] = (gbase + i <= N_NODES) ? rp[gbase + i] : 0;
    }
    __syncthreads();
    for (int bb = 0; bb < NBB; ++bb) {
        int beg = bofs[bb * 8 + s], n = bcnt[bb * 8 + s];
        for (int i = tid; i < n; i += 256) {
            unsigned p = pairs[beg + i];
            int dl = (int)(p >> 17);
            if (dl >= nlo && dl < nhi) {
                int li = dl - nlo;
                int pos = atomicAdd(&lcur[li], 1);
                colv[lrp[li] + pos] = (int)(p & 0x1FFFFu);
            }
        }
    }
}

// ---------------- weight prep: ALL weights in one dispatch, fragment-major bf16 ----------------
__global__ void k_wprep_all(const float* __restrict__ g0, const float* __restrict__ g1,
                            const float* __restrict__ g2, const float* __restrict__ g3,
                            const float* __restrict__ g4, const float* __restrict__ g5,
                            const float* __restrict__ l1w, const float* __restrict__ l2w,
                            unsigned short* __restrict__ dst) {
    int idx = blockIdx.x * 256 + threadIdx.x;
    if (idx >= WPREP_TOT) return;
    const float* w; int local, K, O;
    if (idx < 98304) {
        int r = idx >> 14; local = idx & 16383; K = 128; O = 128;
        w = r == 0 ? g0 : r == 1 ? g1 : r == 2 ? g2 : r == 3 ? g3 : r == 4 ? g4 : g5;
    } else if (idx < 245760) {
        local = idx - 98304; K = 384; O = 384; w = l1w;
    } else {
        local = idx - 245760; K = 384; O = 40; w = l2w;
    }
    int kss = K >> 5;
    int e = local & 7, lane = (local >> 3) & 63, rest = local >> 9;
    int ks = rest % kss, ot = rest / kss;
    int c = ot * 16 + (lane & 15);
    int k = ks * 32 + (lane >> 4) * 8 + e;
    float v = (c < O) ? w[k * O + c] : 0.f;
    dst[idx] = f2bf(v);
}

// ---------------- x -> sliced bf16 layout [4][N][32] ----------------
__global__ void k_xprep(const float* __restrict__ x, unsigned short* __restrict__ xs) {
    int s = blockIdx.x & 3;
    int rest = (blockIdx.x >> 2) * 256 + threadIdx.x;   // dword index within slice, N*16
    if (rest >= N_NODES * 16) return;
    int n = rest >> 4, wrd = rest & 15;
    float2 v = *(const float2*)(x + (size_t)n * 128 + s * 32 + wrd * 2);
    ((unsigned*)xs)[(size_t)s * N_NODES * 16 + rest] =
        (unsigned)f2bf(v.x) | ((unsigned)f2bf(v.y) << 16);
}

// ---------------- aggregation: 4 slices x 64B rows, 4 lanes/edge, 8-deep gather ----------------
__device__ __forceinline__ void acc8(float* acc, uint4 f, float m) {
    unsigned u[4] = {f.x, f.y, f.z, f.w};
    for (int d = 0; d < 4; ++d) {
        acc[2 * d]     = fmaf(m, bf2f((unsigned short)u[d]), acc[2 * d]);
        acc[2 * d + 1] = fmaf(m, bf2f((unsigned short)(u[d] >> 16)), acc[2 * d + 1]);
    }
}

__global__ __launch_bounds__(512) void k_aggs(const unsigned short* __restrict__ feat,
                                              unsigned short* __restrict__ tout,
                                              const int* __restrict__ rp,
                                              const int* __restrict__ colv) {
    __shared__ int scol[COLV_LDS + 8];
    __shared__ int srp[AGG_NODES + 1];
    const int s = blockIdx.x & 3;
    const int chunk = blockIdx.x >> 2;
    const int tid = threadIdx.x;
    const int nbase = chunk * AGG_NODES;

    for (int i = tid; i <= AGG_NODES; i += 512) {
        int n = nbase + i;
        srp[i] = rp[n <= N_NODES ? n : N_NODES];
    }
    __syncthreads();
    const int ebase = srp[0];
    const int ecount = srp[AGG_NODES] - ebase;
    const int elds = ecount < COLV_LDS ? ecount : COLV_LDS;
    for (int i = tid; i < elds; i += 512) scol[i] = colv[ebase + i];
    if (tid < 8) scol[elds + tid] = 0;
    __syncthreads();

    const unsigned* fs = (const unsigned*)feat + (size_t)s * N_NODES * 16;
    unsigned* ts = (unsigned*)tout + (size_t)s * N_NODES * 16;

    const int sub = tid >> 2, q = tid & 3;      // 4 lanes per node, q*16B of the 64B row
    const int node = nbase + sub;
    if (node >= N_NODES) return;
    const int off = q * 4;                       // dwords
    const int e0 = srp[sub] - ebase, e1 = srp[sub + 1] - ebase;

    float acc[8];
    {
        uint4 a = *(const uint4*)(fs + (size_t)node * 16 + off);
        unsigned u[4] = {a.x, a.y, a.z, a.w};
        for (int d = 0; d < 4; ++d) {
            acc[2 * d]     = bf2f((unsigned short)u[d]);
            acc[2 * d + 1] = bf2f((unsigned short)(u[d] >> 16));
        }
    }

    if (ecount <= COLV_LDS) {
        int e = e0;
        const int efull = e0 + ((e1 - e0) & ~7);
        for (; e < efull; e += 8) {
            int j[8];
            #pragma unroll
            for (int k = 0; k < 8; ++k) j[k] = scol[e + k];
            uint4 f[8];
            #pragma unroll
            for (int k = 0; k < 8; ++k)
                f[k] = *(const uint4*)(fs + (size_t)j[k] * 16 + off);
            #pragma unroll
            for (int k = 0; k < 8; ++k) acc8(acc, f[k], 1.f);
        }
        if (e < e1) {
            int j[8]; float m[8];
            #pragma unroll
            for (int k = 0; k < 8; ++k) {
                int ee = e + k;
                bool v = ee < e1;
                j[k] = v ? scol[ee] : node;
                m[k] = v ? 1.f : 0.f;
            }
            uint4 f[8];
            #pragma unroll
            for (int k = 0; k < 8; ++k)
                f[k] = *(const uint4*)(fs + (size_t)j[k] * 16 + off);
            #pragma unroll
            for (int k = 0; k < 8; ++k) acc8(acc, f[k], m[k]);
        }
    } else {
        for (int e = e0; e < e1; e += 8) {
            int j[8]; float m[8];
            #pragma unroll
            for (int k = 0; k < 8; ++k) {
                int ee = e + k;
                bool v = ee < e1;
                int idx = ee < COLV_LDS ? scol[ee] : colv[ebase + ee];
                j[k] = v ? idx : node;
                m[k] = v ? 1.f : 0.f;
            }
            uint4 f[8];
            #pragma unroll
            for (int k = 0; k < 8; ++k)
                f[k] = *(const uint4*)(fs + (size_t)j[k] * 16 + off);
            #pragma unroll
            for (int k = 0; k < 8; ++k) acc8(acc, f[k], m[k]);
        }
    }

    uint4 o;
    o.x = (unsigned)f2bf(acc[0]) | ((unsigned)f2bf(acc[1]) << 16);
    o.y = (unsigned)f2bf(acc[2]) | ((unsigned)f2bf(acc[3]) << 16);
    o.z = (unsigned)f2bf(acc[4]) | ((unsigned)f2bf(acc[5]) << 16);
    o.w = (unsigned)f2bf(acc[6]) | ((unsigned)f2bf(acc[7]) << 16);
    *(uint4*)(ts + (size_t)node * 16 + off) = o;
}

// ---------------- fused GIN MLP, M=128, [4][N][32] layout, half-rotation LDS ----------------
// Sub-tile [slice][128 rows][64B] (8KB); physical 16B-slot = h ^ ((row>>1)&3).
__global__ __launch_bounds__(512) void k_mlp(
    const unsigned short* __restrict__ tin,
    const unsigned short* __restrict__ w1t, const float* __restrict__ b1,
    const unsigned short* __restrict__ w2t, const float* __restrict__ b2,
    unsigned short* __restrict__ hout) {
    __shared__ __align__(16) char tlds[4 * 8192];
    __shared__ __align__(16) char hlds[4 * 8192];
    const int tid = threadIdx.x, lane = tid & 63, w = tid >> 6;
    const int l15 = lane & 15, lg = lane >> 4;
    const int nbase = blockIdx.x * 128;
    const int rx = (l15 >> 1) & 3;     // ((row>>1)&3) for row = m*16 + l15

    // stage: 32 chunks of 1KB (16 nodes x 64B of one slice), source-half rotated
    #pragma unroll
    for (int i = 0; i < 4; ++i) {
        int c = w + i * 8;                 // chunk id [0,32)
        int s = c >> 3, rblk = c & 7;
        int node = nbase + rblk * 16 + (lane >> 2);
        if (node >= N_NODES) node = 0;
        int hsrc = (lane & 3) ^ ((lane >> 3) & 3);
        gld16(tin + ((size_t)s * N_NODES + node) * 32 + hsrc * 8,
              tlds + c * 1024);
    }

    // preload B1 AND B2 (wave w owns ot = w); B2 latency hides behind GEMM1
    bf16x8 B1[4], B2[4];
    const int col = w * 16 + l15;
    const float bias1 = b1[col], bias2 = b2[col];
    #pragma unroll
    for (int ks = 0; ks < 4; ++ks) {
        B1[ks] = *(const bf16x8*)(w1t + ((size_t)(w * 4 + ks) * 64 + lane) * 8);
        B2[ks] = *(const bf16x8*)(w2t + ((size_t)(w * 4 + ks) * 64 + lane) * 8);
    }
    __syncthreads();   // vmcnt(0) drains staging

    // GEMM1 -> relu -> hlds
    {
        const int hoff = ((lg ^ rx) << 4);
        bf16x8 A[2][4];
        #pragma unroll
        for (int ks = 0; ks < 4; ++ks)
            A[0][ks] = *(const bf16x8*)(tlds + ks * 8192 + l15 * 64 + hoff);
        #pragma unroll
        for (int m = 0; m < 8; ++m) {
            int cur = m & 1, nxt = cur ^ 1;
            if (m < 7) {
                int row = (m + 1) * 16 + l15;
                #pragma unroll
                for (int ks = 0; ks < 4; ++ks)
                    A[nxt][ks] = *(const bf16x8*)(tlds + ks * 8192 + row * 64 + hoff);
            }
            f32x4 acc = {0.f, 0.f, 0.f, 0.f};
            #pragma unroll
            for (int ks = 0; ks < 4; ++ks)
                acc = __builtin_amdgcn_mfma_f32_16x16x32_bf16(A[cur][ks], B1[ks], acc, 0, 0, 0);
            #pragma unroll
            for (int r = 0; r < 4; ++r) {
                int row = m * 16 + lg * 4 + r;
                int rw = (2 * lg + (r >> 1)) & 3;
                int h = (w & 1) * 2 + (l15 >> 3);
                float v = acc[r] + bias1; v = v > 0.f ? v : 0.f;
                *(unsigned short*)(hlds + (w >> 1) * 8192 + row * 64 +
                                   ((h ^ rw) << 4) + (l15 & 7) * 2) = f2bf(v);
            }
        }
    }
    __syncthreads();

    // GEMM2 -> relu -> global ([4][N][32] layout)
    {
        const int hoff = ((lg ^ rx) << 4);
        bf16x8 A[2][4];
        #pragma unroll
        for (int ks = 0; ks < 4; ++ks)
            A[0][ks] = *(const bf16x8*)(hlds + ks * 8192 + l15 * 64 + hoff);
        #pragma unroll
        for (int m = 0; m < 8; ++m) {
            int cur = m & 1, nxt = cur ^ 1;
            if (m < 7) {
                int row = (m + 1) * 16 + l15;
                #pragma unroll
                for (int ks = 0; ks < 4; ++ks)
                    A[nxt][ks] = *(const bf16x8*)(hlds + ks * 8192 + row * 64 + hoff);
            }
            f32x4 acc = {0.f, 0.f, 0.f, 0.f};
            #pragma unroll
            for (int ks = 0; ks < 4; ++ks)
                acc = __builtin_amdgcn_mfma_f32_16x16x32_bf16(A[cur][ks], B2[ks], acc, 0, 0, 0);
            #pragma unroll
            for (int r = 0; r < 4; ++r) {
                int node = nbase + m * 16 + lg * 4 + r;
                if (node < N_NODES) {
                    float v = acc[r] + bias2; v = v > 0.f ? v : 0.f;
                    hout[((size_t)(w >> 1) * N_NODES + node) * 32 + (w & 1) * 16 + l15] = f2bf(v);
                }
            }
        }
    }
}

// ---------------- fused head, M=64, [4][N][32] layout, 48KB LDS -> 2 blocks/CU ----------------
// 12 sub-tiles [64][64B] (4KB). ks in [0,12): part = ks>>2, slice = ks&3.
__global__ __launch_bounds__(512, 4) void k_final(
    const unsigned short* __restrict__ h1, const unsigned short* __restrict__ h2,
    const unsigned short* __restrict__ h3,
    const unsigned short* __restrict__ l1t, const float* __restrict__ l1b,
    const unsigned short* __restrict__ l2t, const float* __restrict__ l2b,
    float* __restrict__ out) {
    __shared__ __align__(16) char lds[12 * 4096];   // 48KB
    const int tid = threadIdx.x, lane = tid & 63, w = tid >> 6;
    const int l15 = lane & 15, lg = lane >> 4;
    const int nbase = blockIdx.x * 64;
    const int rx = (l15 >> 1) & 3;

    // stage: 48 chunks of 1KB; chunk c: sub-tile g=c>>2 (part=g>>2, slice=g&3), rows [(c&3)*16,+16)
    #pragma unroll
    for (int i = 0; i < 6; ++i) {
        int c = w + i * 8;                  // chunk id [0,48)
        int g = c >> 2, rblk = c & 3;
        int part = g >> 2, slice = g & 3;
        int node = nbase + rblk * 16 + (lane >> 2);
        if (node >= N_NODES) node = 0;
        int hsrc = (lane & 3) ^ ((lane >> 3) & 3);
        const unsigned short* hp = part == 0 ? h1 : (part == 1 ? h2 : h3);
        gld16(hp + ((size_t)slice * N_NODES + node) * 32 + hsrc * 8,
              lds + c * 1024);
    }

    // preload lin1 B for ks=0
    bf16x8 B[2][3];
    #pragma unroll
    for (int ot = 0; ot < 3; ++ot)
        B[0][ot] = *(const bf16x8*)(l1t + ((size_t)((w * 3 + ot) * 12) * 64 + lane) * 8);
    __syncthreads();   // vmcnt(0) drains staging

    // lin1: wave w owns out cols [48w, 48w+48), 4 m-tiles; B double-buffered
    f32x4 acc[4][3];
    #pragma unroll
    for (int m = 0; m < 4; ++m)
        #pragma unroll
        for (int ot = 0; ot < 3; ++ot) acc[m][ot] = {0.f, 0.f, 0.f, 0.f};
    {
        const int hoff = ((lg ^ rx) << 4);
        #pragma unroll
        for (int ks = 0; ks < 12; ++ks) {
            int cur = ks & 1, nxt = cur ^ 1;
            if (ks < 11) {
                #pragma unroll
                for (int ot = 0; ot < 3; ++ot)
                    B[nxt][ot] = *(const bf16x8*)(l1t + ((size_t)((w * 3 + ot) * 12 + ks + 1) * 64 + lane) * 8);
            }
            bf16x8 A[4];
            #pragma unroll
            for (int m = 0; m < 4; ++m) {
                int row = m * 16 + l15;
                A[m] = *(const bf16x8*)(lds + ks * 4096 + row * 64 + hoff);
            }
            #pragma unroll
            for (int ot = 0; ot < 3; ++ot)
                #pragma unroll
                for (int m = 0; m < 4; ++m)
                    acc[m][ot] = __builtin_amdgcn_mfma_f32_16x16x32_bf16(A[m], B[cur][ot], acc[m][ot], 0, 0, 0);
        }
    }
    __syncthreads();   // everyone done reading A-tile

    // relu + write hidden (bf16) into same LDS; hidden col c -> group c>>5, half (c>>3)&3
    #pragma unroll
    for (int ot = 0; ot < 3; ++ot) {
        int c = (w * 3 + ot) * 16 + l15;
        int gc = c >> 5, h = (c >> 3) & 3, b2i = (c & 7) * 2;
        float bias = l1b[c];
        #pragma unroll
        for (int m = 0; m < 4; ++m)
            #pragma unroll
            for (int r = 0; r < 4; ++r) {
                int row = m * 16 + lg * 4 + r;
                int rw = (2 * lg + (r >> 1)) & 3;
                float v = acc[m][ot][r] + bias; v = v > 0.f ? v : 0.f;
                *(unsigned short*)(lds + gc * 4096 + row * 64 + ((h ^ rw) << 4) + b2i) = f2bf(v);
            }
    }
    __syncthreads();

    // lin2 + softmax: waves 0-3 own rows [16w,+16) of the 64
    if (w < 4) {
        f32x4 acc2[3];
        #pragma unroll
        for (int ot = 0; ot < 3; ++ot) acc2[ot] = {0.f, 0.f, 0.f, 0.f};
        {
            const int row = w * 16 + l15;
            const int hoff = ((lg ^ rx) << 4);
            bf16x8 C2[2][3];
            #pragma unroll
            for (int ot = 0; ot < 3; ++ot)
                C2[0][ot] = *(const bf16x8*)(l2t + ((size_t)(ot * 12) * 64 + lane) * 8);
            #pragma unroll
            for (int ks = 0; ks < 12; ++ks) {
                int cur = ks & 1, nxt = cur ^ 1;
                if (ks < 11) {
                    #pragma unroll
                    for (int ot = 0; ot < 3; ++ot)
                        C2[nxt][ot] = *(const bf16x8*)(l2t + ((size_t)(ot * 12 + ks + 1) * 64 + lane) * 8);
                }
                bf16x8 A2 = *(const bf16x8*)(lds + ks * 4096 + row * 64 + hoff);
                #pragma unroll
                for (int ot = 0; ot < 3; ++ot)
                    acc2[ot] = __builtin_amdgcn_mfma_f32_16x16x32_bf16(A2, C2[cur][ot], acc2[ot], 0, 0, 0);
            }
        }

        int c0 = l15;
        #pragma unroll
        for (int r = 0; r < 4; ++r) {
            float v0 = acc2[0][r] + l2b[c0];
            float v1 = acc2[1][r] + l2b[c0 + 16];
            float v2 = (c0 < 8) ? (acc2[2][r] + l2b[c0 + 32]) : -1e30f;
            float mx = fmaxf(fmaxf(v0, v1), v2);
            for (int msk = 1; msk < 16; msk <<= 1) mx = fmaxf(mx, __shfl_xor(mx, msk));
            float s = __expf(v0 - mx) + __expf(v1 - mx) + ((c0 < 8) ? __expf(v2 - mx) : 0.f);
            for (int msk = 1; msk < 16; msk <<= 1) s += __shfl_xor(s, msk);
            float lse = mx + __logf(s);
            int node = nbase + w * 16 + lg * 4 + r;
            if (node < N_NODES) {
                out[(size_t)node * 40 + c0] = v0 - lse;
                out[(size_t)node * 40 + c0 + 16] = v1 - lse;
                if (c0 < 8) out[(size_t)node * 40 + c0 + 32] = v2 - lse;
            }
        }
    }
}

extern "C" void kernel_launch(void* const* d_in, const int* in_sizes, int n_in,
                              void* d_out, int out_size, void* d_ws, size_t ws_size,
                              hipStream_t stream) {
    const float* x  = (const float*)d_in[0];
    const int*   ei = (const int*)d_in[1];
    const float* gw1[3] = {(const float*)d_in[2],  (const float*)d_in[6],  (const float*)d_in[10]};
    const float* gb1[3] = {(const float*)d_in[3],  (const float*)d_in[7],  (const float*)d_in[11]};
    const float* gw2[3] = {(const float*)d_in[4],  (const float*)d_in[8],  (const float*)d_in[12]};
    const float* gb2[3] = {(const float*)d_in[5],  (const float*)d_in[9],  (const float*)d_in[13]};
    const float* l1w = (const float*)d_in[14];
    const float* l1b = (const float*)d_in[15];
    const float* l2w = (const float*)d_in[16];
    const float* l2b = (const float*)d_in[17];
    float* out = (float*)d_out;

    char* p = (char*)d_ws;
    auto alloc = [&](size_t bytes) { char* q = p; p += (bytes + 255) & ~(size_t)255; return q; };
    int* rp    = (int*)alloc(4 * (N_NODES + 1));
    int* cnt   = (int*)alloc(4 * N_NODES);
    int* bsum  = (int*)alloc(4 * 256);
    int* bofs  = (int*)alloc(4 * NBB * 8);
    int* bcnt  = (int*)alloc(4 * NBB * 8);
    unsigned* pairs = (unsigned*)alloc(4 * (size_t)NEDGE);
    int* colv  = (int*)alloc(4 * (size_t)NEDGE);
    unsigned short* t  = (unsigned short*)alloc(2 * (size_t)N_NODES * 128);
    unsigned short* h1 = (unsigned short*)alloc(2 * (size_t)N_NODES * 128);
    unsigned short* h2 = (unsigned short*)alloc(2 * (size_t)N_NODES * 128);
    unsigned short* h3 = (unsigned short*)alloc(2 * (size_t)N_NODES * 128);
    unsigned short* xs = h3;   // alias: xs dead after layer-1 agg, h3 written in layer 3
    unsigned short* wt[6];
    for (int i = 0; i < 6; ++i) wt[i] = (unsigned short*)alloc(2 * 128 * 128);
    unsigned short* l1t = (unsigned short*)alloc(2 * 384 * 384);
    unsigned short* l2t = (unsigned short*)alloc(2 * 48 * 384);

    const int nb = (N_NODES + 1023) / 1024;     // 98
    // CSR build: one-pass ballot bucketing + subrange-exclusive count/fill (no global atomics)
    k_bucket<<<NBB, 256, 0, stream>>>(ei, pairs, bofs, bcnt);
    k_cnt3<<<8 * 64, 256, 0, stream>>>(pairs, bofs, bcnt, cnt);
    k_scan1<<<nb, 256, 0, stream>>>(cnt, rp, bsum);
    k_scan2<<<1, 256, 0, stream>>>(bsum, nb);
    k_scan3<<<nb, 256, 0, stream>>>(rp, bsum);
    k_fill3<<<8 * 64, 256, 0, stream>>>(pairs, bofs, bcnt, rp, colv);

    // weight prep (one dispatch, fragment-major bf16)
    k_wprep_all<<<(WPREP_TOT + 255) / 256, 256, 0, stream>>>(
        gw1[0], gw2[0], gw1[1], gw2[1], gw1[2], gw2[2], l1w, l2w, wt[0]);

    // x -> sliced bf16 [4][N][32]
    k_xprep<<<4 * ((N_NODES * 16 + 255) / 256), 256, 0, stream>>>(x, xs);

    const int gagg = ((N_NODES + AGG_NODES - 1) / AGG_NODES) * 4;
    const int gtile2 = (N_NODES + 127) / 128;
    const int gtile1 = (N_NODES + 63) / 64;
    // layer 1
    k_aggs<<<gagg, 512, 0, stream>>>(xs, t, rp, colv);
    k_mlp<<<gtile2, 512, 0, stream>>>(t, wt[0], gb1[0], wt[1], gb2[0], h1);
    // layer 2
    k_aggs<<<gagg, 512, 0, stream>>>(h1, t, rp, colv);
    k_mlp<<<gtile2, 512, 0, stream>>>(t, wt[2], gb1[1], wt[3], gb2[1], h2);
    // layer 3
    k_aggs<<<gagg, 512, 0, stream>>>(h2, t, rp, colv);
    k_mlp<<<gtile2, 512, 0, stream>>>(t, wt[4], gb1[2], wt[5], gb2[2], h3);
    // head
    k_final<<<gtile1, 512, 0, stream>>>(h1, h2, h3, l1t, l1b, l2t, l2b, out);
}

// Round 17
// 505.564 us; speedup vs baseline: 2.0304x; 2.0304x over previous
//
#include <hip/hip_runtime.h>

#define N_NODES 100000
#define NEDGE   1600000
#define NHID    128
#define NCLASS  40

#define AGG_NODES 128
#define COLV_LDS  3072
#define FILL_RANGE  12500   // N_NODES / 8
#define WPREP_TOT   264192  // 6*16384 + 147456 + 18432
#define EPB 2048            // edges per k_bucket block
#define NBB 782             // (NEDGE + EPB - 1) / EPB
#define SUBN 196            // nodes per cnt4/fill4 block (64 * 196 >= 12500)

using bf16x8 = __attribute__((ext_vector_type(8))) short;
using f32x4  = __attribute__((ext_vector_type(4))) float;

__device__ __forceinline__ float bf2f(unsigned short s) {
    unsigned u = ((unsigned)s) << 16; float f; __builtin_memcpy(&f, &u, 4); return f;
}
__device__ __forceinline__ unsigned short f2bf(float f) {
    unsigned u; __builtin_memcpy(&u, &f, 4);
    u = u + 0x7fffu + ((u >> 16) & 1u);          // RNE
    return (unsigned short)(u >> 16);
}

// global -> LDS direct (16B/lane). Dest: wave-uniform base; HW adds lane*16.
__device__ __forceinline__ void gld16(const void* g, void* l) {
    __builtin_amdgcn_global_load_lds(g, l, 16, 0, 0);
}

// ---------------- CSR build: ballot bucket -> slice-contiguous -> LDS count/fill ----------------
__global__ __launch_bounds__(256) void k_bucket(const int* __restrict__ ei,
                                                unsigned* __restrict__ pairs,
                                                int* __restrict__ bofs, int* __restrict__ bcnt) {
    __shared__ int wcnt[4][8];
    __shared__ int wbase[4][8];
    __shared__ int sbase[9];
    const int tid = threadIdx.x, lane = tid & 63, w = tid >> 6;
    const int e0 = blockIdx.x * EPB;
    const unsigned long long below = (1ull << lane) - 1ull;

    int dl[8], src[8], sl[8], posw[8];
    int cnt[8] = {0, 0, 0, 0, 0, 0, 0, 0};   // wave-uniform (same ballots all lanes)
    #pragma unroll
    for (int k = 0; k < 8; ++k) {
        int e = e0 + w * 512 + k * 64 + lane;
        bool v = e < NEDGE;
        int d = v ? ei[NEDGE + e] : -1;
        src[k] = v ? ei[e] : 0;
        int slc = v ? d / FILL_RANGE : -1;
        sl[k] = slc;
        dl[k] = v ? d - slc * FILL_RANGE : 0;
        posw[k] = 0;
        #pragma unroll
        for (int s = 0; s < 8; ++s) {
            unsigned long long mask = __ballot(slc == s);
            if (slc == s) posw[k] = cnt[s] + (int)__popcll(mask & below);
            cnt[s] += (int)__popcll(mask);
        }
    }
    if (lane == 0) {
        #pragma unroll
        for (int s = 0; s < 8; ++s) wcnt[w][s] = cnt[s];
    }
    __syncthreads();
    if (tid == 0) {
        int run = 0;
        for (int s = 0; s < 8; ++s) {
            sbase[s] = run;
            for (int w2 = 0; w2 < 4; ++w2) { wbase[w2][s] = run; run += wcnt[w2][s]; }
        }
        sbase[8] = run;
        for (int s = 0; s < 8; ++s) {
            bofs[blockIdx.x * 8 + s] = e0 + sbase[s];
            bcnt[blockIdx.x * 8 + s] = sbase[s + 1] - sbase[s];
        }
    }
    __syncthreads();
    #pragma unroll
    for (int k = 0; k < 8; ++k) {
        if (sl[k] >= 0)
            pairs[e0 + wbase[w][sl[k]] + posw[k]] = ((unsigned)dl[k] << 17) | (unsigned)src[k];
    }
}

// per-slice exclusive prefix over block counts: pbase[bb][s], stot[s]. Block = slice.
__global__ void k_sseg(const int* __restrict__ bcnt, int* __restrict__ pbase, int* __restrict__ stot) {
    __shared__ int sh[256];
    const int s = blockIdx.x, t = threadIdx.x;
    int v[4]; int sum = 0;
    #pragma unroll
    for (int k = 0; k < 4; ++k) {
        int i = t * 4 + k;
        v[k] = (i < NBB) ? bcnt[i * 8 + s] : 0;
        sum += v[k];
    }
    sh[t] = sum; __syncthreads();
    for (int off = 1; off < 256; off <<= 1) {
        int x = (t >= off) ? sh[t - off] : 0;
        __syncthreads();
        sh[t] += x;
        __syncthreads();
    }
    int excl = sh[t] - sum;
    #pragma unroll
    for (int k = 0; k < 4; ++k) {
        int i = t * 4 + k;
        if (i < NBB) pbase[i * 8 + s] = excl;
        excl += v[k];
    }
    if (t == 255) stot[s] = sh[255];
}

// slice bases (16B-aligned), sentinel-pad the alignment gaps.
__global__ void k_sbase(const int* __restrict__ stot, int* __restrict__ sbase,
                        unsigned* __restrict__ pairs2) {
    if (threadIdx.x || blockIdx.x) return;
    int run = 0;
    for (int s = 0; s < 8; ++s) {
        sbase[s] = run;
        int end = run + stot[s];
        run = (end + 3) & ~3;
        for (int i = end; i < run; ++i) pairs2[i] = 0xFFFFFFFFu;   // dl=32767 -> filtered
    }
    sbase[8] = run;
}

// copy block-local segments into globally slice-contiguous pairs2 (coalesced).
__global__ __launch_bounds__(256) void k_scatter(const unsigned* __restrict__ pairs,
                                                 const int* __restrict__ bcnt,
                                                 const int* __restrict__ pbase,
                                                 const int* __restrict__ sbase,
                                                 unsigned* __restrict__ pairs2) {
    __shared__ int lb[9], ldst[8];
    const int bb = blockIdx.x, tid = threadIdx.x;
    if (tid == 0) {
        int run = 0;
        for (int s = 0; s < 8; ++s) {
            lb[s] = run; run += bcnt[bb * 8 + s];
            ldst[s] = sbase[s] + pbase[bb * 8 + s];
        }
        lb[8] = run;
    }
    __syncthreads();
    const int nblk = lb[8];
    for (int i = tid; i < nblk; i += 256) {
        int s = 0;
        #pragma unroll
        for (int j = 1; j < 8; ++j) s += (i >= lb[j]);
        pairs2[ldst[s] + (i - lb[s])] = pairs[(size_t)bb * EPB + i];
    }
}

// subrange-exclusive count: dense uint4 stream of the slice (L2-resident), LDS table,
// cnt written contiguously -> ZERO global atomics.
__global__ __launch_bounds__(256) void k_cnt4(const unsigned* __restrict__ pairs2,
                                              const int* __restrict__ sbase,
                                              int* __restrict__ cnt) {
    __shared__ int lcnt[SUBN];
    const int s = blockIdx.x & 7, sub = blockIdx.x >> 3;
    const int nlo = sub * SUBN;
    const int nhi = (nlo + SUBN < FILL_RANGE) ? nlo + SUBN : FILL_RANGE;
    const int tid = threadIdx.x;
    for (int i = tid; i < SUBN; i += 256) lcnt[i] = 0;
    __syncthreads();
    const int beg = sbase[s];
    const int n4 = (sbase[s + 1] - beg) >> 2;
    const uint4* p4 = (const uint4*)(pairs2 + beg);
    for (int i = tid; i < n4; i += 256) {
        uint4 q = p4[i];
        int d0 = (int)(q.x >> 17), d1 = (int)(q.y >> 17);
        int d2 = (int)(q.z >> 17), d3 = (int)(q.w >> 17);
        if (d0 >= nlo && d0 < nhi) atomicAdd(&lcnt[d0 - nlo], 1);
        if (d1 >= nlo && d1 < nhi) atomicAdd(&lcnt[d1 - nlo], 1);
        if (d2 >= nlo && d2 < nhi) atomicAdd(&lcnt[d2 - nlo], 1);
        if (d3 >= nlo && d3 < nhi) atomicAdd(&lcnt[d3 - nlo], 1);
    }
    __syncthreads();
    const int base = s * FILL_RANGE + nlo;
    for (int i = tid; i < nhi - nlo; i += 256) cnt[base + i] = lcnt[i];
}

__global__ void k_scan1(const int* __restrict__ cnt, int* __restrict__ rp, int* __restrict__ bsum) {
    __shared__ int sh[256];
    int t = threadIdx.x, base = blockIdx.x * 1024;
    int v[4]; int s = 0;
    for (int k = 0; k < 4; ++k) { int i = base + t * 4 + k; v[k] = (i < N_NODES) ? cnt[i] : 0; s += v[k]; }
    sh[t] = s; __syncthreads();
    for (int off = 1; off < 256; off <<= 1) {
        int x = (t >= off) ? sh[t - off] : 0;
        __syncthreads();
        sh[t] += x;
        __syncthreads();
    }
    int excl = sh[t] - s;
    for (int k = 0; k < 4; ++k) { int i = base + t * 4 + k; if (i < N_NODES) rp[i] = excl; excl += v[k]; }
    if (t == 255) bsum[blockIdx.x] = sh[255];
}

__global__ void k_scan2(int* __restrict__ bsum, int nb) {
    __shared__ int sh[256];
    int t = threadIdx.x;
    int v = (t < nb) ? bsum[t] : 0;
    sh[t] = v; __syncthreads();
    for (int off = 1; off < 256; off <<= 1) {
        int x = (t >= off) ? sh[t - off] : 0;
        __syncthreads();
        sh[t] += x;
        __syncthreads();
    }
    if (t < nb) bsum[t] = sh[t] - v;   // exclusive block offsets
}

__global__ void k_scan3(int* __restrict__ rp, const int* __restrict__ bsum) {
    int base = blockIdx.x * 1024;
    int off = bsum[blockIdx.x];
    for (int k = 0; k < 4; ++k) {
        int i = base + threadIdx.x * 4 + k;
        if (i < N_NODES) rp[i] += off;
    }
    if (blockIdx.x == 0 && threadIdx.x == 0) rp[N_NODES] = NEDGE;
}

// subrange-exclusive fill: dense uint4 stream, LDS cursors, colv in exclusive window.
__global__ __launch_bounds__(256) void k_fill4(const unsigned* __restrict__ pairs2,
                                               const int* __restrict__ sbase,
                                               const int* __restrict__ rp,
                                               int* __restrict__ colv) {
    __shared__ int lcur[SUBN];
    __shared__ int lrp[SUBN];
    const int s = blockIdx.x & 7, sub = blockIdx.x >> 3;
    const int nlo = sub * SUBN;
    const int nhi = (nlo + SUBN < FILL_RANGE) ? nlo + SUBN : FILL_RANGE;
    const int tid = threadIdx.x;
    const int gbase = s * FILL_RANGE + nlo;
    for (int i = tid; i < SUBN; i += 256) {
        lcur[i] = 0;
        lrp[i] = (i < nhi - nlo) ? rp[gbase + i] : 0;
    }
    __syncthreads();
    const int beg = sbase[s];
    const int n4 = (sbase[s + 1] - beg) >> 2;
    const uint4* p4 = (const uint4*)(pairs2 + beg);
    for (int i = tid; i < n4; i += 256) {
        uint4 q = p4[i];
        unsigned e[4] = {q.x, q.y, q.z, q.w};
        #pragma unroll
        for (int k = 0; k < 4; ++k) {
            int dl = (int)(e[k] >> 17);
            if (dl >= nlo && dl < nhi) {
                int li = dl - nlo;
                int pos = atomicAdd(&lcur[li], 1);
                colv[lrp[li] + pos] = (int)(e[k] & 0x1FFFFu);
            }
        }
    }
}

// ---------------- weight prep: ALL weights in one dispatch, fragment-major bf16 ----------------
__global__ void k_wprep_all(const float* __restrict__ g0, const float* __restrict__ g1,
                            const float* __restrict__ g2, const float* __restrict__ g3,
                            const float* __restrict__ g4, const float* __restrict__ g5,
                            const float* __restrict__ l1w, const float* __restrict__ l2w,
                            unsigned short* __restrict__ dst) {
    int idx = blockIdx.x * 256 + threadIdx.x;
    if (idx >= WPREP_TOT) return;
    const float* w; int local, K, O;
    if (idx < 98304) {
        int r = idx >> 14; local = idx & 16383; K = 128; O = 128;
        w = r == 0 ? g0 : r == 1 ? g1 : r == 2 ? g2 : r == 3 ? g3 : r == 4 ? g4 : g5;
    } else if (idx < 245760) {
        local = idx - 98304; K = 384; O = 384; w = l1w;
    } else {
        local = idx - 245760; K = 384; O = 40; w = l2w;
    }
    int kss = K >> 5;
    int e = local & 7, lane = (local >> 3) & 63, rest = local >> 9;
    int ks = rest % kss, ot = rest / kss;
    int c = ot * 16 + (lane & 15);
    int k = ks * 32 + (lane >> 4) * 8 + e;
    float v = (c < O) ? w[k * O + c] : 0.f;
    dst[idx] = f2bf(v);
}

// ---------------- x -> sliced bf16 layout [4][N][32] ----------------
__global__ void k_xprep(const float* __restrict__ x, unsigned short* __restrict__ xs) {
    int s = blockIdx.x & 3;
    int rest = (blockIdx.x >> 2) * 256 + threadIdx.x;   // dword index within slice, N*16
    if (rest >= N_NODES * 16) return;
    int n = rest >> 4, wrd = rest & 15;
    float2 v = *(const float2*)(x + (size_t)n * 128 + s * 32 + wrd * 2);
    ((unsigned*)xs)[(size_t)s * N_NODES * 16 + rest] =
        (unsigned)f2bf(v.x) | ((unsigned)f2bf(v.y) << 16);
}

// ---------------- aggregation: 4 slices x 64B rows, 4 lanes/edge, 8-deep gather ----------------
__device__ __forceinline__ void acc8(float* acc, uint4 f, float m) {
    unsigned u[4] = {f.x, f.y, f.z, f.w};
    for (int d = 0; d < 4; ++d) {
        acc[2 * d]     = fmaf(m, bf2f((unsigned short)u[d]), acc[2 * d]);
        acc[2 * d + 1] = fmaf(m, bf2f((unsigned short)(u[d] >> 16)), acc[2 * d + 1]);
    }
}

__global__ __launch_bounds__(512) void k_aggs(const unsigned short* __restrict__ feat,
                                              unsigned short* __restrict__ tout,
                                              const int* __restrict__ rp,
                                              const int* __restrict__ colv) {
    __shared__ int scol[COLV_LDS + 8];
    __shared__ int srp[AGG_NODES + 1];
    const int s = blockIdx.x & 3;
    const int chunk = blockIdx.x >> 2;
    const int tid = threadIdx.x;
    const int nbase = chunk * AGG_NODES;

    for (int i = tid; i <= AGG_NODES; i += 512) {
        int n = nbase + i;
        srp[i] = rp[n <= N_NODES ? n : N_NODES];
    }
    __syncthreads();
    const int ebase = srp[0];
    const int ecount = srp[AGG_NODES] - ebase;
    const int elds = ecount < COLV_LDS ? ecount : COLV_LDS;
    for (int i = tid; i < elds; i += 512) scol[i] = colv[ebase + i];
    if (tid < 8) scol[elds + tid] = 0;
    __syncthreads();

    const unsigned* fs = (const unsigned*)feat + (size_t)s * N_NODES * 16;
    unsigned* ts = (unsigned*)tout + (size_t)s * N_NODES * 16;

    const int sub = tid >> 2, q = tid & 3;      // 4 lanes per node, q*16B of the 64B row
    const int node = nbase + sub;
    if (node >= N_NODES) return;
    const int off = q * 4;                       // dwords
    const int e0 = srp[sub] - ebase, e1 = srp[sub + 1] - ebase;

    float acc[8];
    {
        uint4 a = *(const uint4*)(fs + (size_t)node * 16 + off);
        unsigned u[4] = {a.x, a.y, a.z, a.w};
        for (int d = 0; d < 4; ++d) {
            acc[2 * d]     = bf2f((unsigned short)u[d]);
            acc[2 * d + 1] = bf2f((unsigned short)(u[d] >> 16));
        }
    }

    if (ecount <= COLV_LDS) {
        int e = e0;
        const int efull = e0 + ((e1 - e0) & ~7);
        for (; e < efull; e += 8) {
            int j[8];
            #pragma unroll
            for (int k = 0; k < 8; ++k) j[k] = scol[e + k];
            uint4 f[8];
            #pragma unroll
            for (int k = 0; k < 8; ++k)
                f[k] = *(const uint4*)(fs + (size_t)j[k] * 16 + off);
            #pragma unroll
            for (int k = 0; k < 8; ++k) acc8(acc, f[k], 1.f);
        }
        if (e < e1) {
            int j[8]; float m[8];
            #pragma unroll
            for (int k = 0; k < 8; ++k) {
                int ee = e + k;
                bool v = ee < e1;
                j[k] = v ? scol[ee] : node;
                m[k] = v ? 1.f : 0.f;
            }
            uint4 f[8];
            #pragma unroll
            for (int k = 0; k < 8; ++k)
                f[k] = *(const uint4*)(fs + (size_t)j[k] * 16 + off);
            #pragma unroll
            for (int k = 0; k < 8; ++k) acc8(acc, f[k], m[k]);
        }
    } else {
        for (int e = e0; e < e1; e += 8) {
            int j[8]; float m[8];
            #pragma unroll
            for (int k = 0; k < 8; ++k) {
                int ee = e + k;
                bool v = ee < e1;
                int idx = ee < COLV_LDS ? scol[ee] : colv[ebase + ee];
                j[k] = v ? idx : node;
                m[k] = v ? 1.f : 0.f;
            }
            uint4 f[8];
            #pragma unroll
            for (int k = 0; k < 8; ++k)
                f[k] = *(const uint4*)(fs + (size_t)j[k] * 16 + off);
            #pragma unroll
            for (int k = 0; k < 8; ++k) acc8(acc, f[k], m[k]);
        }
    }

    uint4 o;
    o.x = (unsigned)f2bf(acc[0]) | ((unsigned)f2bf(acc[1]) << 16);
    o.y = (unsigned)f2bf(acc[2]) | ((unsigned)f2bf(acc[3]) << 16);
    o.z = (unsigned)f2bf(acc[4]) | ((unsigned)f2bf(acc[5]) << 16);
    o.w = (unsigned)f2bf(acc[6]) | ((unsigned)f2bf(acc[7]) << 16);
    *(uint4*)(ts + (size_t)node * 16 + off) = o;
}

// ---------------- fused GIN MLP, M=128, [4][N][32] layout, half-rotation LDS ----------------
__global__ __launch_bounds__(512) void k_mlp(
    const unsigned short* __restrict__ tin,
    const unsigned short* __restrict__ w1t, const float* __restrict__ b1,
    const unsigned short* __restrict__ w2t, const float* __restrict__ b2,
    unsigned short* __restrict__ hout) {
    __shared__ __align__(16) char tlds[4 * 8192];
    __shared__ __align__(16) char hlds[4 * 8192];
    const int tid = threadIdx.x, lane = tid & 63, w = tid >> 6;
    const int l15 = lane & 15, lg = lane >> 4;
    const int nbase = blockIdx.x * 128;
    const int rx = (l15 >> 1) & 3;     // ((row>>1)&3) for row = m*16 + l15

    #pragma unroll
    for (int i = 0; i < 4; ++i) {
        int c = w + i * 8;                 // chunk id [0,32)
        int s = c >> 3, rblk = c & 7;
        int node = nbase + rblk * 16 + (lane >> 2);
        if (node >= N_NODES) node = 0;
        int hsrc = (lane & 3) ^ ((lane >> 3) & 3);
        gld16(tin + ((size_t)s * N_NODES + node) * 32 + hsrc * 8,
              tlds + c * 1024);
    }

    bf16x8 B1[4], B2[4];
    const int col = w * 16 + l15;
    const float bias1 = b1[col], bias2 = b2[col];
    #pragma unroll
    for (int ks = 0; ks < 4; ++ks) {
        B1[ks] = *(const bf16x8*)(w1t + ((size_t)(w * 4 + ks) * 64 + lane) * 8);
        B2[ks] = *(const bf16x8*)(w2t + ((size_t)(w * 4 + ks) * 64 + lane) * 8);
    }
    __syncthreads();   // vmcnt(0) drains staging

    {
        const int hoff = ((lg ^ rx) << 4);
        bf16x8 A[2][4];
        #pragma unroll
        for (int ks = 0; ks < 4; ++ks)
            A[0][ks] = *(const bf16x8*)(tlds + ks * 8192 + l15 * 64 + hoff);
        #pragma unroll
        for (int m = 0; m < 8; ++m) {
            int cur = m & 1, nxt = cur ^ 1;
            if (m < 7) {
                int row = (m + 1) * 16 + l15;
                #pragma unroll
                for (int ks = 0; ks < 4; ++ks)
                    A[nxt][ks] = *(const bf16x8*)(tlds + ks * 8192 + row * 64 + hoff);
            }
            f32x4 acc = {0.f, 0.f, 0.f, 0.f};
            #pragma unroll
            for (int ks = 0; ks < 4; ++ks)
                acc = __builtin_amdgcn_mfma_f32_16x16x32_bf16(A[cur][ks], B1[ks], acc, 0, 0, 0);
            #pragma unroll
            for (int r = 0; r < 4; ++r) {
                int row = m * 16 + lg * 4 + r;
                int rw = (2 * lg + (r >> 1)) & 3;
                int h = (w & 1) * 2 + (l15 >> 3);
                float v = acc[r] + bias1; v = v > 0.f ? v : 0.f;
                *(unsigned short*)(hlds + (w >> 1) * 8192 + row * 64 +
                                   ((h ^ rw) << 4) + (l15 & 7) * 2) = f2bf(v);
            }
        }
    }
    __syncthreads();

    {
        const int hoff = ((lg ^ rx) << 4);
        bf16x8 A[2][4];
        #pragma unroll
        for (int ks = 0; ks < 4; ++ks)
            A[0][ks] = *(const bf16x8*)(hlds + ks * 8192 + l15 * 64 + hoff);
        #pragma unroll
        for (int m = 0; m < 8; ++m) {
            int cur = m & 1, nxt = cur ^ 1;
            if (m < 7) {
                int row = (m + 1) * 16 + l15;
                #pragma unroll
                for (int ks = 0; ks < 4; ++ks)
                    A[nxt][ks] = *(const bf16x8*)(hlds + ks * 8192 + row * 64 + hoff);
            }
            f32x4 acc = {0.f, 0.f, 0.f, 0.f};
            #pragma unroll
            for (int ks = 0; ks < 4; ++ks)
                acc = __builtin_amdgcn_mfma_f32_16x16x32_bf16(A[cur][ks], B2[ks], acc, 0, 0, 0);
            #pragma unroll
            for (int r = 0; r < 4; ++r) {
                int node = nbase + m * 16 + lg * 4 + r;
                if (node < N_NODES) {
                    float v = acc[r] + bias2; v = v > 0.f ? v : 0.f;
                    hout[((size_t)(w >> 1) * N_NODES + node) * 32 + (w & 1) * 16 + l15] = f2bf(v);
                }
            }
        }
    }
}

// ---------------- fused head, M=64, [4][N][32] layout, 48KB LDS -> 2 blocks/CU ----------------
__global__ __launch_bounds__(512, 4) void k_final(
    const unsigned short* __restrict__ h1, const unsigned short* __restrict__ h2,
    const unsigned short* __restrict__ h3,
    const unsigned short* __restrict__ l1t, const float* __restrict__ l1b,
    const unsigned short* __restrict__ l2t, const float* __restrict__ l2b,
    float* __restrict__ out) {
    __shared__ __align__(16) char lds[12 * 4096];   // 48KB
    const int tid = threadIdx.x, lane = tid & 63, w = tid >> 6;
    const int l15 = lane & 15, lg = lane >> 4;
    const int nbase = blockIdx.x * 64;
    const int rx = (l15 >> 1) & 3;

    #pragma unroll
    for (int i = 0; i < 6; ++i) {
        int c = w + i * 8;                  // chunk id [0,48)
        int g = c >> 2, rblk = c & 3;
        int part = g >> 2, slice = g & 3;
        int node = nbase + rblk * 16 + (lane >> 2);
        if (node >= N_NODES) node = 0;
        int hsrc = (lane & 3) ^ ((lane >> 3) & 3);
        const unsigned short* hp = part == 0 ? h1 : (part == 1 ? h2 : h3);
        gld16(hp + ((size_t)slice * N_NODES + node) * 32 + hsrc * 8,
              lds + c * 1024);
    }

    bf16x8 B[2][3];
    #pragma unroll
    for (int ot = 0; ot < 3; ++ot)
        B[0][ot] = *(const bf16x8*)(l1t + ((size_t)((w * 3 + ot) * 12) * 64 + lane) * 8);
    __syncthreads();   // vmcnt(0) drains staging

    f32x4 acc[4][3];
    #pragma unroll
    for (int m = 0; m < 4; ++m)
        #pragma unroll
        for (int ot = 0; ot < 3; ++ot) acc[m][ot] = {0.f, 0.f, 0.f, 0.f};
    {
        const int hoff = ((lg ^ rx) << 4);
        #pragma unroll
        for (int ks = 0; ks < 12; ++ks) {
            int cur = ks & 1, nxt = cur ^ 1;
            if (ks < 11) {
                #pragma unroll
                for (int ot = 0; ot < 3; ++ot)
                    B[nxt][ot] = *(const bf16x8*)(l1t + ((size_t)((w * 3 + ot) * 12 + ks + 1) * 64 + lane) * 8);
            }
            bf16x8 A[4];
            #pragma unroll
            for (int m = 0; m < 4; ++m) {
                int row = m * 16 + l15;
                A[m] = *(const bf16x8*)(lds + ks * 4096 + row * 64 + hoff);
            }
            #pragma unroll
            for (int ot = 0; ot < 3; ++ot)
                #pragma unroll
                for (int m = 0; m < 4; ++m)
                    acc[m][ot] = __builtin_amdgcn_mfma_f32_16x16x32_bf16(A[m], B[cur][ot], acc[m][ot], 0, 0, 0);
        }
    }
    __syncthreads();   // everyone done reading A-tile

    #pragma unroll
    for (int ot = 0; ot < 3; ++ot) {
        int c = (w * 3 + ot) * 16 + l15;
        int gc = c >> 5, h = (c >> 3) & 3, b2i = (c & 7) * 2;
        float bias = l1b[c];
        #pragma unroll
        for (int m = 0; m < 4; ++m)
            #pragma unroll
            for (int r = 0; r < 4; ++r) {
                int row = m * 16 + lg * 4 + r;
                int rw = (2 * lg + (r >> 1)) & 3;
                float v = acc[m][ot][r] + bias; v = v > 0.f ? v : 0.f;
                *(unsigned short*)(lds + gc * 4096 + row * 64 + ((h ^ rw) << 4) + b2i) = f2bf(v);
            }
    }
    __syncthreads();

    if (w < 4) {
        f32x4 acc2[3];
        #pragma unroll
        for (int ot = 0; ot < 3; ++ot) acc2[ot] = {0.f, 0.f, 0.f, 0.f};
        {
            const int row = w * 16 + l15;
            const int hoff = ((lg ^ rx) << 4);
            bf16x8 C2[2][3];
            #pragma unroll
            for (int ot = 0; ot < 3; ++ot)
                C2[0][ot] = *(const bf16x8*)(l2t + ((size_t)(ot * 12) * 64 + lane) * 8);
            #pragma unroll
            for (int ks = 0; ks < 12; ++ks) {
                int cur = ks & 1, nxt = cur ^ 1;
                if (ks < 11) {
                    #pragma unroll
                    for (int ot = 0; ot < 3; ++ot)
                        C2[nxt][ot] = *(const bf16x8*)(l2t + ((size_t)(ot * 12 + ks + 1) * 64 + lane) * 8);
                }
                bf16x8 A2 = *(const bf16x8*)(lds + ks * 4096 + row * 64 + hoff);
                #pragma unroll
                for (int ot = 0; ot < 3; ++ot)
                    acc2[ot] = __builtin_amdgcn_mfma_f32_16x16x32_bf16(A2, C2[cur][ot], acc2[ot], 0, 0, 0);
            }
        }

        int c0 = l15;
        #pragma unroll
        for (int r = 0; r < 4; ++r) {
            float v0 = acc2[0][r] + l2b[c0];
            float v1 = acc2[1][r] + l2b[c0 + 16];
            float v2 = (c0 < 8) ? (acc2[2][r] + l2b[c0 + 32]) : -1e30f;
            float mx = fmaxf(fmaxf(v0, v1), v2);
            for (int msk = 1; msk < 16; msk <<= 1) mx = fmaxf(mx, __shfl_xor(mx, msk));
            float s = __expf(v0 - mx) + __expf(v1 - mx) + ((c0 < 8) ? __expf(v2 - mx) : 0.f);
            for (int msk = 1; msk < 16; msk <<= 1) s += __shfl_xor(s, msk);
            float lse = mx + __logf(s);
            int node = nbase + w * 16 + lg * 4 + r;
            if (node < N_NODES) {
                out[(size_t)node * 40 + c0] = v0 - lse;
                out[(size_t)node * 40 + c0 + 16] = v1 - lse;
                if (c0 < 8) out[(size_t)node * 40 + c0 + 32] = v2 - lse;
            }
        }
    }
}

extern "C" void kernel_launch(void* const* d_in, const int* in_sizes, int n_in,
                              void* d_out, int out_size, void* d_ws, size_t ws_size,
                              hipStream_t stream) {
    const float* x  = (const float*)d_in[0];
    const int*   ei = (const int*)d_in[1];
    const float* gw1[3] = {(const float*)d_in[2],  (const float*)d_in[6],  (const float*)d_in[10]};
    const float* gb1[3] = {(const float*)d_in[3],  (const float*)d_in[7],  (const float*)d_in[11]};
    const float* gw2[3] = {(const float*)d_in[4],  (const float*)d_in[8],  (const float*)d_in[12]};
    const float* gb2[3] = {(const float*)d_in[5],  (const float*)d_in[9],  (const float*)d_in[13]};
    const float* l1w = (const float*)d_in[14];
    const float* l1b = (const float*)d_in[15];
    const float* l2w = (const float*)d_in[16];
    const float* l2b = (const float*)d_in[17];
    float* out = (float*)d_out;

    char* p = (char*)d_ws;
    auto alloc = [&](size_t bytes) { char* q = p; p += (bytes + 255) & ~(size_t)255; return q; };
    int* rp    = (int*)alloc(4 * (N_NODES + 1));
    int* cnt   = (int*)alloc(4 * N_NODES);
    int* bsum  = (int*)alloc(4 * 256);
    int* bofs  = (int*)alloc(4 * NBB * 8);
    int* bcnt  = (int*)alloc(4 * NBB * 8);
    int* pbase = (int*)alloc(4 * NBB * 8);
    int* stot  = (int*)alloc(4 * 16);
    int* sbase = (int*)alloc(4 * 16);
    unsigned* pairs  = (unsigned*)alloc(4 * (size_t)NEDGE);
    unsigned* pairs2 = (unsigned*)alloc(4 * ((size_t)NEDGE + 64));
    int* colv  = (int*)alloc(4 * (size_t)NEDGE);
    unsigned short* t  = (unsigned short*)alloc(2 * (size_t)N_NODES * 128);
    unsigned short* h1 = (unsigned short*)alloc(2 * (size_t)N_NODES * 128);
    unsigned short* h2 = (unsigned short*)alloc(2 * (size_t)N_NODES * 128);
    unsigned short* h3 = (unsigned short*)alloc(2 * (size_t)N_NODES * 128);
    unsigned short* xs = h3;   // alias: xs dead after layer-1 agg, h3 written in layer 3
    unsigned short* wt[6];
    for (int i = 0; i < 6; ++i) wt[i] = (unsigned short*)alloc(2 * 128 * 128);
    unsigned short* l1t = (unsigned short*)alloc(2 * 384 * 384);
    unsigned short* l2t = (unsigned short*)alloc(2 * 48 * 384);

    const int nb = (N_NODES + 1023) / 1024;     // 98
    // CSR build: ballot bucket -> slice-contiguous pairs2 -> LDS count/fill (no global atomics)
    k_bucket<<<NBB, 256, 0, stream>>>(ei, pairs, bofs, bcnt);
    k_sseg<<<8, 256, 0, stream>>>(bcnt, pbase, stot);
    k_sbase<<<1, 64, 0, stream>>>(stot, sbase, pairs2);
    k_scatter<<<NBB, 256, 0, stream>>>(pairs, bcnt, pbase, sbase, pairs2);
    k_cnt4<<<8 * 64, 256, 0, stream>>>(pairs2, sbase, cnt);
    k_scan1<<<nb, 256, 0, stream>>>(cnt, rp, bsum);
    k_scan2<<<1, 256, 0, stream>>>(bsum, nb);
    k_scan3<<<nb, 256, 0, stream>>>(rp, bsum);
    k_fill4<<<8 * 64, 256, 0, stream>>>(pairs2, sbase, rp, colv);

    // weight prep (one dispatch, fragment-major bf16)
    k_wprep_all<<<(WPREP_TOT + 255) / 256, 256, 0, stream>>>(
        gw1[0], gw2[0], gw1[1], gw2[1], gw1[2], gw2[2], l1w, l2w, wt[0]);

    // x -> sliced bf16 [4][N][32]
    k_xprep<<<4 * ((N_NODES * 16 + 255) / 256), 256, 0, stream>>>(x, xs);

    const int gagg = ((N_NODES + AGG_NODES - 1) / AGG_NODES) * 4;
    const int gtile2 = (N_NODES + 127) / 128;
    const int gtile1 = (N_NODES + 63) / 64;
    // layer 1
    k_aggs<<<gagg, 512, 0, stream>>>(xs, t, rp, colv);
    k_mlp<<<gtile2, 512, 0, stream>>>(t, wt[0], gb1[0], wt[1], gb2[0], h1);
    // layer 2
    k_aggs<<<gagg, 512, 0, stream>>>(h1, t, rp, colv);
    k_mlp<<<gtile2, 512, 0, stream>>>(t, wt[2], gb1[1], wt[3], gb2[1], h2);
    // layer 3
    k_aggs<<<gagg, 512, 0, stream>>>(h2, t, rp, colv);
    k_mlp<<<gtile2, 512, 0, stream>>>(t, wt[4], gb1[2], wt[5], gb2[2], h3);
    // head
    k_final<<<gtile1, 512, 0, stream>>>(h1, h2, h3, l1t, l1b, l2t, l2b, out);
}

// Round 18
// 442.976 us; speedup vs baseline: 2.3173x; 1.1413x over previous
//
#include <hip/hip_runtime.h>

#define N_NODES 100000
#define NEDGE   1600000
#define NHID    128
#define NCLASS  40

#define AGG_NODES 128
#define COLV_LDS  3072
#define FILL_RANGE  12500   // N_NODES / 8
#define WPREP_TOT   264192  // 6*16384 + 147456 + 18432
#define EPB 2048            // edges per k_bucket block
#define NBB 782             // (NEDGE + EPB - 1) / EPB
#define SUBN 782            // nodes per cnt4/fill4 block (16 * 782 >= 12500)
#define NSUB 16             // subranges per slice

using bf16x8 = __attribute__((ext_vector_type(8))) short;
using f32x4  = __attribute__((ext_vector_type(4))) float;

__device__ __forceinline__ float bf2f(unsigned short s) {
    unsigned u = ((unsigned)s) << 16; float f; __builtin_memcpy(&f, &u, 4); return f;
}
__device__ __forceinline__ unsigned short f2bf(float f) {
    unsigned u; __builtin_memcpy(&u, &f, 4);
    u = u + 0x7fffu + ((u >> 16) & 1u);          // RNE
    return (unsigned short)(u >> 16);
}

// global -> LDS direct (16B/lane). Dest: wave-uniform base; HW adds lane*16.
__device__ __forceinline__ void gld16(const void* g, void* l) {
    __builtin_amdgcn_global_load_lds(g, l, 16, 0, 0);
}

// ---------------- CSR build: ballot bucket -> slice-contiguous -> LDS count/fill ----------------
__global__ __launch_bounds__(256) void k_bucket(const int* __restrict__ ei,
                                                unsigned* __restrict__ pairs,
                                                int* __restrict__ bofs, int* __restrict__ bcnt) {
    __shared__ int wcnt[4][8];
    __shared__ int wbase[4][8];
    __shared__ int sbase[9];
    const int tid = threadIdx.x, lane = tid & 63, w = tid >> 6;
    const int e0 = blockIdx.x * EPB;
    const unsigned long long below = (1ull << lane) - 1ull;

    int dl[8], src[8], sl[8], posw[8];
    int cnt[8] = {0, 0, 0, 0, 0, 0, 0, 0};   // wave-uniform (same ballots all lanes)
    #pragma unroll
    for (int k = 0; k < 8; ++k) {
        int e = e0 + w * 512 + k * 64 + lane;
        bool v = e < NEDGE;
        int d = v ? ei[NEDGE + e] : -1;
        src[k] = v ? ei[e] : 0;
        int slc = v ? d / FILL_RANGE : -1;
        sl[k] = slc;
        dl[k] = v ? d - slc * FILL_RANGE : 0;
        posw[k] = 0;
        #pragma unroll
        for (int s = 0; s < 8; ++s) {
            unsigned long long mask = __ballot(slc == s);
            if (slc == s) posw[k] = cnt[s] + (int)__popcll(mask & below);
            cnt[s] += (int)__popcll(mask);
        }
    }
    if (lane == 0) {
        #pragma unroll
        for (int s = 0; s < 8; ++s) wcnt[w][s] = cnt[s];
    }
    __syncthreads();
    if (tid == 0) {
        int run = 0;
        for (int s = 0; s < 8; ++s) {
            sbase[s] = run;
            for (int w2 = 0; w2 < 4; ++w2) { wbase[w2][s] = run; run += wcnt[w2][s]; }
        }
        sbase[8] = run;
        for (int s = 0; s < 8; ++s) {
            bofs[blockIdx.x * 8 + s] = e0 + sbase[s];
            bcnt[blockIdx.x * 8 + s] = sbase[s + 1] - sbase[s];
        }
    }
    __syncthreads();
    #pragma unroll
    for (int k = 0; k < 8; ++k) {
        if (sl[k] >= 0)
            pairs[e0 + wbase[w][sl[k]] + posw[k]] = ((unsigned)dl[k] << 17) | (unsigned)src[k];
    }
}

// per-slice exclusive prefix over block counts: pbase[bb][s], stot[s]. Block = slice.
__global__ void k_sseg(const int* __restrict__ bcnt, int* __restrict__ pbase, int* __restrict__ stot) {
    __shared__ int sh[256];
    const int s = blockIdx.x, t = threadIdx.x;
    int v[4]; int sum = 0;
    #pragma unroll
    for (int k = 0; k < 4; ++k) {
        int i = t * 4 + k;
        v[k] = (i < NBB) ? bcnt[i * 8 + s] : 0;
        sum += v[k];
    }
    sh[t] = sum; __syncthreads();
    for (int off = 1; off < 256; off <<= 1) {
        int x = (t >= off) ? sh[t - off] : 0;
        __syncthreads();
        sh[t] += x;
        __syncthreads();
    }
    int excl = sh[t] - sum;
    #pragma unroll
    for (int k = 0; k < 4; ++k) {
        int i = t * 4 + k;
        if (i < NBB) pbase[i * 8 + s] = excl;
        excl += v[k];
    }
    if (t == 255) stot[s] = sh[255];
}

// slice bases (16B-aligned), sentinel-pad the alignment gaps.
__global__ void k_sbase(const int* __restrict__ stot, int* __restrict__ sbase,
                        unsigned* __restrict__ pairs2) {
    if (threadIdx.x || blockIdx.x) return;
    int run = 0;
    for (int s = 0; s < 8; ++s) {
        sbase[s] = run;
        int end = run + stot[s];
        run = (end + 3) & ~3;
        for (int i = end; i < run; ++i) pairs2[i] = 0xFFFFFFFFu;   // dl=32767 -> filtered
    }
    sbase[8] = run;
}

// copy block-local segments into globally slice-contiguous pairs2 (coalesced).
__global__ __launch_bounds__(256) void k_scatter(const unsigned* __restrict__ pairs,
                                                 const int* __restrict__ bcnt,
                                                 const int* __restrict__ pbase,
                                                 const int* __restrict__ sbase,
                                                 unsigned* __restrict__ pairs2) {
    __shared__ int lb[9], ldst[8];
    const int bb = blockIdx.x, tid = threadIdx.x;
    if (tid == 0) {
        int run = 0;
        for (int s = 0; s < 8; ++s) {
            lb[s] = run; run += bcnt[bb * 8 + s];
            ldst[s] = sbase[s] + pbase[bb * 8 + s];
        }
        lb[8] = run;
    }
    __syncthreads();
    const int nblk = lb[8];
    for (int i = tid; i < nblk; i += 256) {
        int s = 0;
        #pragma unroll
        for (int j = 1; j < 8; ++j) s += (i >= lb[j]);
        pairs2[ldst[s] + (i - lb[s])] = pairs[(size_t)bb * EPB + i];
    }
}

// subrange-exclusive count: dense uint4 stream of the slice (L2-resident), LDS table,
// cnt written contiguously -> ZERO global atomics. 16 subranges/slice.
__global__ __launch_bounds__(512) void k_cnt4(const unsigned* __restrict__ pairs2,
                                              const int* __restrict__ sbase,
                                              int* __restrict__ cnt) {
    __shared__ int lcnt[SUBN];
    const int s = blockIdx.x & 7, sub = blockIdx.x >> 3;
    const int nlo = sub * SUBN;
    const int nhi = (nlo + SUBN < FILL_RANGE) ? nlo + SUBN : FILL_RANGE;
    const int tid = threadIdx.x;
    for (int i = tid; i < SUBN; i += 512) lcnt[i] = 0;
    __syncthreads();
    const int beg = sbase[s];
    const int n4 = (sbase[s + 1] - beg) >> 2;
    const uint4* p4 = (const uint4*)(pairs2 + beg);
    for (int i = tid; i < n4; i += 512) {
        uint4 q = p4[i];
        int d0 = (int)(q.x >> 17), d1 = (int)(q.y >> 17);
        int d2 = (int)(q.z >> 17), d3 = (int)(q.w >> 17);
        if (d0 >= nlo && d0 < nhi) atomicAdd(&lcnt[d0 - nlo], 1);
        if (d1 >= nlo && d1 < nhi) atomicAdd(&lcnt[d1 - nlo], 1);
        if (d2 >= nlo && d2 < nhi) atomicAdd(&lcnt[d2 - nlo], 1);
        if (d3 >= nlo && d3 < nhi) atomicAdd(&lcnt[d3 - nlo], 1);
    }
    __syncthreads();
    const int base = s * FILL_RANGE + nlo;
    for (int i = tid; i < nhi - nlo; i += 512) cnt[base + i] = lcnt[i];
}

__global__ void k_scan1(const int* __restrict__ cnt, int* __restrict__ rp, int* __restrict__ bsum) {
    __shared__ int sh[256];
    int t = threadIdx.x, base = blockIdx.x * 1024;
    int v[4]; int s = 0;
    for (int k = 0; k < 4; ++k) { int i = base + t * 4 + k; v[k] = (i < N_NODES) ? cnt[i] : 0; s += v[k]; }
    sh[t] = s; __syncthreads();
    for (int off = 1; off < 256; off <<= 1) {
        int x = (t >= off) ? sh[t - off] : 0;
        __syncthreads();
        sh[t] += x;
        __syncthreads();
    }
    int excl = sh[t] - s;
    for (int k = 0; k < 4; ++k) { int i = base + t * 4 + k; if (i < N_NODES) rp[i] = excl; excl += v[k]; }
    if (t == 255) bsum[blockIdx.x] = sh[255];
}

__global__ void k_scan2(int* __restrict__ bsum, int nb) {
    __shared__ int sh[256];
    int t = threadIdx.x;
    int v = (t < nb) ? bsum[t] : 0;
    sh[t] = v; __syncthreads();
    for (int off = 1; off < 256; off <<= 1) {
        int x = (t >= off) ? sh[t - off] : 0;
        __syncthreads();
        sh[t] += x;
        __syncthreads();
    }
    if (t < nb) bsum[t] = sh[t] - v;   // exclusive block offsets
}

__global__ void k_scan3(int* __restrict__ rp, const int* __restrict__ bsum) {
    int base = blockIdx.x * 1024;
    int off = bsum[blockIdx.x];
    for (int k = 0; k < 4; ++k) {
        int i = base + threadIdx.x * 4 + k;
        if (i < N_NODES) rp[i] += off;
    }
    if (blockIdx.x == 0 && threadIdx.x == 0) rp[N_NODES] = NEDGE;
}

// subrange-exclusive fill: dense uint4 stream, LDS cursors, colv in exclusive window.
__global__ __launch_bounds__(512) void k_fill4(const unsigned* __restrict__ pairs2,
                                               const int* __restrict__ sbase,
                                               const int* __restrict__ rp,
                                               int* __restrict__ colv) {
    __shared__ int lcur[SUBN];
    __shared__ int lrp[SUBN];
    const int s = blockIdx.x & 7, sub = blockIdx.x >> 3;
    const int nlo = sub * SUBN;
    const int nhi = (nlo + SUBN < FILL_RANGE) ? nlo + SUBN : FILL_RANGE;
    const int tid = threadIdx.x;
    const int gbase = s * FILL_RANGE + nlo;
    for (int i = tid; i < SUBN; i += 512) {
        lcur[i] = 0;
        lrp[i] = (i < nhi - nlo) ? rp[gbase + i] : 0;
    }
    __syncthreads();
    const int beg = sbase[s];
    const int n4 = (sbase[s + 1] - beg) >> 2;
    const uint4* p4 = (const uint4*)(pairs2 + beg);
    for (int i = tid; i < n4; i += 512) {
        uint4 q = p4[i];
        unsigned e[4] = {q.x, q.y, q.z, q.w};
        #pragma unroll
        for (int k = 0; k < 4; ++k) {
            int dl = (int)(e[k] >> 17);
            if (dl >= nlo && dl < nhi) {
                int li = dl - nlo;
                int pos = atomicAdd(&lcur[li], 1);
                colv[lrp[li] + pos] = (int)(e[k] & 0x1FFFFu);
            }
        }
    }
}

// ---------------- weight prep: ALL weights in one dispatch, fragment-major bf16 ----------------
__global__ void k_wprep_all(const float* __restrict__ g0, const float* __restrict__ g1,
                            const float* __restrict__ g2, const float* __restrict__ g3,
                            const float* __restrict__ g4, const float* __restrict__ g5,
                            const float* __restrict__ l1w, const float* __restrict__ l2w,
                            unsigned short* __restrict__ dst) {
    int idx = blockIdx.x * 256 + threadIdx.x;
    if (idx >= WPREP_TOT) return;
    const float* w; int local, K, O;
    if (idx < 98304) {
        int r = idx >> 14; local = idx & 16383; K = 128; O = 128;
        w = r == 0 ? g0 : r == 1 ? g1 : r == 2 ? g2 : r == 3 ? g3 : r == 4 ? g4 : g5;
    } else if (idx < 245760) {
        local = idx - 98304; K = 384; O = 384; w = l1w;
    } else {
        local = idx - 245760; K = 384; O = 40; w = l2w;
    }
    int kss = K >> 5;
    int e = local & 7, lane = (local >> 3) & 63, rest = local >> 9;
    int ks = rest % kss, ot = rest / kss;
    int c = ot * 16 + (lane & 15);
    int k = ks * 32 + (lane >> 4) * 8 + e;
    float v = (c < O) ? w[k * O + c] : 0.f;
    dst[idx] = f2bf(v);
}

// ---------------- x -> sliced bf16 layout [4][N][32] ----------------
__global__ void k_xprep(const float* __restrict__ x, unsigned short* __restrict__ xs) {
    int s = blockIdx.x & 3;
    int rest = (blockIdx.x >> 2) * 256 + threadIdx.x;   // dword index within slice, N*16
    if (rest >= N_NODES * 16) return;
    int n = rest >> 4, wrd = rest & 15;
    float2 v = *(const float2*)(x + (size_t)n * 128 + s * 32 + wrd * 2);
    ((unsigned*)xs)[(size_t)s * N_NODES * 16 + rest] =
        (unsigned)f2bf(v.x) | ((unsigned)f2bf(v.y) << 16);
}

// ---------------- aggregation: 4 slices x 64B rows, 4 lanes/edge, 8-deep gather ----------------
__device__ __forceinline__ void acc8(float* acc, uint4 f, float m) {
    unsigned u[4] = {f.x, f.y, f.z, f.w};
    for (int d = 0; d < 4; ++d) {
        acc[2 * d]     = fmaf(m, bf2f((unsigned short)u[d]), acc[2 * d]);
        acc[2 * d + 1] = fmaf(m, bf2f((unsigned short)(u[d] >> 16)), acc[2 * d + 1]);
    }
}

__global__ __launch_bounds__(512) void k_aggs(const unsigned short* __restrict__ feat,
                                              unsigned short* __restrict__ tout,
                                              const int* __restrict__ rp,
                                              const int* __restrict__ colv) {
    __shared__ int scol[COLV_LDS + 8];
    __shared__ int srp[AGG_NODES + 1];
    const int s = blockIdx.x & 3;
    const int chunk = blockIdx.x >> 2;
    const int tid = threadIdx.x;
    const int nbase = chunk * AGG_NODES;

    for (int i = tid; i <= AGG_NODES; i += 512) {
        int n = nbase + i;
        srp[i] = rp[n <= N_NODES ? n : N_NODES];
    }
    __syncthreads();
    const int ebase = srp[0];
    const int ecount = srp[AGG_NODES] - ebase;
    const int elds = ecount < COLV_LDS ? ecount : COLV_LDS;
    for (int i = tid; i < elds; i += 512) scol[i] = colv[ebase + i];
    if (tid < 8) scol[elds + tid] = 0;
    __syncthreads();

    const unsigned* fs = (const unsigned*)feat + (size_t)s * N_NODES * 16;
    unsigned* ts = (unsigned*)tout + (size_t)s * N_NODES * 16;

    const int sub = tid >> 2, q = tid & 3;      // 4 lanes per node, q*16B of the 64B row
    const int node = nbase + sub;
    if (node >= N_NODES) return;
    const int off = q * 4;                       // dwords
    const int e0 = srp[sub] - ebase, e1 = srp[sub + 1] - ebase;

    float acc[8];
    {
        uint4 a = *(const uint4*)(fs + (size_t)node * 16 + off);
        unsigned u[4] = {a.x, a.y, a.z, a.w};
        for (int d = 0; d < 4; ++d) {
            acc[2 * d]     = bf2f((unsigned short)u[d]);
            acc[2 * d + 1] = bf2f((unsigned short)(u[d] >> 16));
        }
    }

    if (ecount <= COLV_LDS) {
        int e = e0;
        const int efull = e0 + ((e1 - e0) & ~7);
        for (; e < efull; e += 8) {
            int j[8];
            #pragma unroll
            for (int k = 0; k < 8; ++k) j[k] = scol[e + k];
            uint4 f[8];
            #pragma unroll
            for (int k = 0; k < 8; ++k)
                f[k] = *(const uint4*)(fs + (size_t)j[k] * 16 + off);
            #pragma unroll
            for (int k = 0; k < 8; ++k) acc8(acc, f[k], 1.f);
        }
        if (e < e1) {
            int j[8]; float m[8];
            #pragma unroll
            for (int k = 0; k < 8; ++k) {
                int ee = e + k;
                bool v = ee < e1;
                j[k] = v ? scol[ee] : node;
                m[k] = v ? 1.f : 0.f;
            }
            uint4 f[8];
            #pragma unroll
            for (int k = 0; k < 8; ++k)
                f[k] = *(const uint4*)(fs + (size_t)j[k] * 16 + off);
            #pragma unroll
            for (int k = 0; k < 8; ++k) acc8(acc, f[k], m[k]);
        }
    } else {
        for (int e = e0; e < e1; e += 8) {
            int j[8]; float m[8];
            #pragma unroll
            for (int k = 0; k < 8; ++k) {
                int ee = e + k;
                bool v = ee < e1;
                int idx = ee < COLV_LDS ? scol[ee] : colv[ebase + ee];
                j[k] = v ? idx : node;
                m[k] = v ? 1.f : 0.f;
            }
            uint4 f[8];
            #pragma unroll
            for (int k = 0; k < 8; ++k)
                f[k] = *(const uint4*)(fs + (size_t)j[k] * 16 + off);
            #pragma unroll
            for (int k = 0; k < 8; ++k) acc8(acc, f[k], m[k]);
        }
    }

    uint4 o;
    o.x = (unsigned)f2bf(acc[0]) | ((unsigned)f2bf(acc[1]) << 16);
    o.y = (unsigned)f2bf(acc[2]) | ((unsigned)f2bf(acc[3]) << 16);
    o.z = (unsigned)f2bf(acc[4]) | ((unsigned)f2bf(acc[5]) << 16);
    o.w = (unsigned)f2bf(acc[6]) | ((unsigned)f2bf(acc[7]) << 16);
    *(uint4*)(ts + (size_t)node * 16 + off) = o;
}

// ---------------- fused GIN MLP, M=128, [4][N][32] layout, half-rotation LDS ----------------
__global__ __launch_bounds__(512) void k_mlp(
    const unsigned short* __restrict__ tin,
    const unsigned short* __restrict__ w1t, const float* __restrict__ b1,
    const unsigned short* __restrict__ w2t, const float* __restrict__ b2,
    unsigned short* __restrict__ hout) {
    __shared__ __align__(16) char tlds[4 * 8192];
    __shared__ __align__(16) char hlds[4 * 8192];
    const int tid = threadIdx.x, lane = tid & 63, w = tid >> 6;
    const int l15 = lane & 15, lg = lane >> 4;
    const int nbase = blockIdx.x * 128;
    const int rx = (l15 >> 1) & 3;     // ((row>>1)&3) for row = m*16 + l15

    #pragma unroll
    for (int i = 0; i < 4; ++i) {
        int c = w + i * 8;                 // chunk id [0,32)
        int s = c >> 3, rblk = c & 7;
        int node = nbase + rblk * 16 + (lane >> 2);
        if (node >= N_NODES) node = 0;
        int hsrc = (lane & 3) ^ ((lane >> 3) & 3);
        gld16(tin + ((size_t)s * N_NODES + node) * 32 + hsrc * 8,
              tlds + c * 1024);
    }

    bf16x8 B1[4], B2[4];
    const int col = w * 16 + l15;
    const float bias1 = b1[col], bias2 = b2[col];
    #pragma unroll
    for (int ks = 0; ks < 4; ++ks) {
        B1[ks] = *(const bf16x8*)(w1t + ((size_t)(w * 4 + ks) * 64 + lane) * 8);
        B2[ks] = *(const bf16x8*)(w2t + ((size_t)(w * 4 + ks) * 64 + lane) * 8);
    }
    __syncthreads();   // vmcnt(0) drains staging

    {
        const int hoff = ((lg ^ rx) << 4);
        bf16x8 A[2][4];
        #pragma unroll
        for (int ks = 0; ks < 4; ++ks)
            A[0][ks] = *(const bf16x8*)(tlds + ks * 8192 + l15 * 64 + hoff);
        #pragma unroll
        for (int m = 0; m < 8; ++m) {
            int cur = m & 1, nxt = cur ^ 1;
            if (m < 7) {
                int row = (m + 1) * 16 + l15;
                #pragma unroll
                for (int ks = 0; ks < 4; ++ks)
                    A[nxt][ks] = *(const bf16x8*)(tlds + ks * 8192 + row * 64 + hoff);
            }
            f32x4 acc = {0.f, 0.f, 0.f, 0.f};
            #pragma unroll
            for (int ks = 0; ks < 4; ++ks)
                acc = __builtin_amdgcn_mfma_f32_16x16x32_bf16(A[cur][ks], B1[ks], acc, 0, 0, 0);
            #pragma unroll
            for (int r = 0; r < 4; ++r) {
                int row = m * 16 + lg * 4 + r;
                int rw = (2 * lg + (r >> 1)) & 3;
                int h = (w & 1) * 2 + (l15 >> 3);
                float v = acc[r] + bias1; v = v > 0.f ? v : 0.f;
                *(unsigned short*)(hlds + (w >> 1) * 8192 + row * 64 +
                                   ((h ^ rw) << 4) + (l15 & 7) * 2) = f2bf(v);
            }
        }
    }
    __syncthreads();

    {
        const int hoff = ((lg ^ rx) << 4);
        bf16x8 A[2][4];
        #pragma unroll
        for (int ks = 0; ks < 4; ++ks)
            A[0][ks] = *(const bf16x8*)(hlds + ks * 8192 + l15 * 64 + hoff);
        #pragma unroll
        for (int m = 0; m < 8; ++m) {
            int cur = m & 1, nxt = cur ^ 1;
            if (m < 7) {
                int row = (m + 1) * 16 + l15;
                #pragma unroll
                for (int ks = 0; ks < 4; ++ks)
                    A[nxt][ks] = *(const bf16x8*)(hlds + ks * 8192 + row * 64 + hoff);
            }
            f32x4 acc = {0.f, 0.f, 0.f, 0.f};
            #pragma unroll
            for (int ks = 0; ks < 4; ++ks)
                acc = __builtin_amdgcn_mfma_f32_16x16x32_bf16(A[cur][ks], B2[ks], acc, 0, 0, 0);
            #pragma unroll
            for (int r = 0; r < 4; ++r) {
                int node = nbase + m * 16 + lg * 4 + r;
                if (node < N_NODES) {
                    float v = acc[r] + bias2; v = v > 0.f ? v : 0.f;
                    hout[((size_t)(w >> 1) * N_NODES + node) * 32 + (w & 1) * 16 + l15] = f2bf(v);
                }
            }
        }
    }
}

// ---------------- fused head, M=64, [4][N][32] layout, 48KB LDS -> 2 blocks/CU ----------------
__global__ __launch_bounds__(512, 4) void k_final(
    const unsigned short* __restrict__ h1, const unsigned short* __restrict__ h2,
    const unsigned short* __restrict__ h3,
    const unsigned short* __restrict__ l1t, const float* __restrict__ l1b,
    const unsigned short* __restrict__ l2t, const float* __restrict__ l2b,
    float* __restrict__ out) {
    __shared__ __align__(16) char lds[12 * 4096];   // 48KB
    const int tid = threadIdx.x, lane = tid & 63, w = tid >> 6;
    const int l15 = lane & 15, lg = lane >> 4;
    const int nbase = blockIdx.x * 64;
    const int rx = (l15 >> 1) & 3;

    #pragma unroll
    for (int i = 0; i < 6; ++i) {
        int c = w + i * 8;                  // chunk id [0,48)
        int g = c >> 2, rblk = c & 3;
        int part = g >> 2, slice = g & 3;
        int node = nbase + rblk * 16 + (lane >> 2);
        if (node >= N_NODES) node = 0;
        int hsrc = (lane & 3) ^ ((lane >> 3) & 3);
        const unsigned short* hp = part == 0 ? h1 : (part == 1 ? h2 : h3);
        gld16(hp + ((size_t)slice * N_NODES + node) * 32 + hsrc * 8,
              lds + c * 1024);
    }

    bf16x8 B[2][3];
    #pragma unroll
    for (int ot = 0; ot < 3; ++ot)
        B[0][ot] = *(const bf16x8*)(l1t + ((size_t)((w * 3 + ot) * 12) * 64 + lane) * 8);
    __syncthreads();   // vmcnt(0) drains staging

    f32x4 acc[4][3];
    #pragma unroll
    for (int m = 0; m < 4; ++m)
        #pragma unroll
        for (int ot = 0; ot < 3; ++ot) acc[m][ot] = {0.f, 0.f, 0.f, 0.f};
    {
        const int hoff = ((lg ^ rx) << 4);
        #pragma unroll
        for (int ks = 0; ks < 12; ++ks) {
            int cur = ks & 1, nxt = cur ^ 1;
            if (ks < 11) {
                #pragma unroll
                for (int ot = 0; ot < 3; ++ot)
                    B[nxt][ot] = *(const bf16x8*)(l1t + ((size_t)((w * 3 + ot) * 12 + ks + 1) * 64 + lane) * 8);
            }
            bf16x8 A[4];
            #pragma unroll
            for (int m = 0; m < 4; ++m) {
                int row = m * 16 + l15;
                A[m] = *(const bf16x8*)(lds + ks * 4096 + row * 64 + hoff);
            }
            #pragma unroll
            for (int ot = 0; ot < 3; ++ot)
                #pragma unroll
                for (int m = 0; m < 4; ++m)
                    acc[m][ot] = __builtin_amdgcn_mfma_f32_16x16x32_bf16(A[m], B[cur][ot], acc[m][ot], 0, 0, 0);
        }
    }
    __syncthreads();   // everyone done reading A-tile

    #pragma unroll
    for (int ot = 0; ot < 3; ++ot) {
        int c = (w * 3 + ot) * 16 + l15;
        int gc = c >> 5, h = (c >> 3) & 3, b2i = (c & 7) * 2;
        float bias = l1b[c];
        #pragma unroll
        for (int m = 0; m < 4; ++m)
            #pragma unroll
            for (int r = 0; r < 4; ++r) {
                int row = m * 16 + lg * 4 + r;
                int rw = (2 * lg + (r >> 1)) & 3;
                float v = acc[m][ot][r] + bias; v = v > 0.f ? v : 0.f;
                *(unsigned short*)(lds + gc * 4096 + row * 64 + ((h ^ rw) << 4) + b2i) = f2bf(v);
            }
    }
    __syncthreads();

    if (w < 4) {
        f32x4 acc2[3];
        #pragma unroll
        for (int ot = 0; ot < 3; ++ot) acc2[ot] = {0.f, 0.f, 0.f, 0.f};
        {
            const int row = w * 16 + l15;
            const int hoff = ((lg ^ rx) << 4);
            bf16x8 C2[2][3];
            #pragma unroll
            for (int ot = 0; ot < 3; ++ot)
                C2[0][ot] = *(const bf16x8*)(l2t + ((size_t)(ot * 12) * 64 + lane) * 8);
            #pragma unroll
            for (int ks = 0; ks < 12; ++ks) {
                int cur = ks & 1, nxt = cur ^ 1;
                if (ks < 11) {
                    #pragma unroll
                    for (int ot = 0; ot < 3; ++ot)
                        C2[nxt][ot] = *(const bf16x8*)(l2t + ((size_t)(ot * 12 + ks + 1) * 64 + lane) * 8);
                }
                bf16x8 A2 = *(const bf16x8*)(lds + ks * 4096 + row * 64 + hoff);
                #pragma unroll
                for (int ot = 0; ot < 3; ++ot)
                    acc2[ot] = __builtin_amdgcn_mfma_f32_16x16x32_bf16(A2, C2[cur][ot], acc2[ot], 0, 0, 0);
            }
        }

        int c0 = l15;
        #pragma unroll
        for (int r = 0; r < 4; ++r) {
            float v0 = acc2[0][r] + l2b[c0];
            float v1 = acc2[1][r] + l2b[c0 + 16];
            float v2 = (c0 < 8) ? (acc2[2][r] + l2b[c0 + 32]) : -1e30f;
            float mx = fmaxf(fmaxf(v0, v1), v2);
            for (int msk = 1; msk < 16; msk <<= 1) mx = fmaxf(mx, __shfl_xor(mx, msk));
            float s = __expf(v0 - mx) + __expf(v1 - mx) + ((c0 < 8) ? __expf(v2 - mx) : 0.f);
            for (int msk = 1; msk < 16; msk <<= 1) s += __shfl_xor(s, msk);
            float lse = mx + __logf(s);
            int node = nbase + w * 16 + lg * 4 + r;
            if (node < N_NODES) {
                out[(size_t)node * 40 + c0] = v0 - lse;
                out[(size_t)node * 40 + c0 + 16] = v1 - lse;
                if (c0 < 8) out[(size_t)node * 40 + c0 + 32] = v2 - lse;
            }
        }
    }
}

extern "C" void kernel_launch(void* const* d_in, const int* in_sizes, int n_in,
                              void* d_out, int out_size, void* d_ws, size_t ws_size,
                              hipStream_t stream) {
    const float* x  = (const float*)d_in[0];
    const int*   ei = (const int*)d_in[1];
    const float* gw1[3] = {(const float*)d_in[2],  (const float*)d_in[6],  (const float*)d_in[10]};
    const float* gb1[3] = {(const float*)d_in[3],  (const float*)d_in[7],  (const float*)d_in[11]};
    const float* gw2[3] = {(const float*)d_in[4],  (const float*)d_in[8],  (const float*)d_in[12]};
    const float* gb2[3] = {(const float*)d_in[5],  (const float*)d_in[9],  (const float*)d_in[13]};
    const float* l1w = (const float*)d_in[14];
    const float* l1b = (const float*)d_in[15];
    const float* l2w = (const float*)d_in[16];
    const float* l2b = (const float*)d_in[17];
    float* out = (float*)d_out;

    char* p = (char*)d_ws;
    auto alloc = [&](size_t bytes) { char* q = p; p += (bytes + 255) & ~(size_t)255; return q; };
    int* rp    = (int*)alloc(4 * (N_NODES + 1));
    int* cnt   = (int*)alloc(4 * N_NODES);
    int* bsum  = (int*)alloc(4 * 256);
    int* bofs  = (int*)alloc(4 * NBB * 8);
    int* bcnt  = (int*)alloc(4 * NBB * 8);
    int* pbase = (int*)alloc(4 * NBB * 8);
    int* stot  = (int*)alloc(4 * 16);
    int* sbase = (int*)alloc(4 * 16);
    unsigned* pairs  = (unsigned*)alloc(4 * (size_t)NEDGE);
    unsigned* pairs2 = (unsigned*)alloc(4 * ((size_t)NEDGE + 64));
    int* colv  = (int*)alloc(4 * (size_t)NEDGE);
    unsigned short* t  = (unsigned short*)alloc(2 * (size_t)N_NODES * 128);
    unsigned short* h1 = (unsigned short*)alloc(2 * (size_t)N_NODES * 128);
    unsigned short* h2 = (unsigned short*)alloc(2 * (size_t)N_NODES * 128);
    unsigned short* h3 = (unsigned short*)alloc(2 * (size_t)N_NODES * 128);
    unsigned short* xs = h3;   // alias: xs dead after layer-1 agg, h3 written in layer 3
    unsigned short* wt[6];
    for (int i = 0; i < 6; ++i) wt[i] = (unsigned short*)alloc(2 * 128 * 128);
    unsigned short* l1t = (unsigned short*)alloc(2 * 384 * 384);
    unsigned short* l2t = (unsigned short*)alloc(2 * 48 * 384);

    const int nb = (N_NODES + 1023) / 1024;     // 98
    // CSR build: ballot bucket -> slice-contiguous pairs2 -> LDS count/fill (no global atomics)
    k_bucket<<<NBB, 256, 0, stream>>>(ei, pairs, bofs, bcnt);
    k_sseg<<<8, 256, 0, stream>>>(bcnt, pbase, stot);
    k_sbase<<<1, 64, 0, stream>>>(stot, sbase, pairs2);
    k_scatter<<<NBB, 256, 0, stream>>>(pairs, bcnt, pbase, sbase, pairs2);
    k_cnt4<<<8 * NSUB, 512, 0, stream>>>(pairs2, sbase, cnt);
    k_scan1<<<nb, 256, 0, stream>>>(cnt, rp, bsum);
    k_scan2<<<1, 256, 0, stream>>>(bsum, nb);
    k_scan3<<<nb, 256, 0, stream>>>(rp, bsum);
    k_fill4<<<8 * NSUB, 512, 0, stream>>>(pairs2, sbase, rp, colv);

    // weight prep (one dispatch, fragment-major bf16)
    k_wprep_all<<<(WPREP_TOT + 255) / 256, 256, 0, stream>>>(
        gw1[0], gw2[0], gw1[1], gw2[1], gw1[2], gw2[2], l1w, l2w, wt[0]);

    // x -> sliced bf16 [4][N][32]
    k_xprep<<<4 * ((N_NODES * 16 + 255) / 256), 256, 0, stream>>>(x, xs);

    const int gagg = ((N_NODES + AGG_NODES - 1) / AGG_NODES) * 4;
    const int gtile2 = (N_NODES + 127) / 128;
    const int gtile1 = (N_NODES + 63) / 64;
    // layer 1
    k_aggs<<<gagg, 512, 0, stream>>>(xs, t, rp, colv);
    k_mlp<<<gtile2, 512, 0, stream>>>(t, wt[0], gb1[0], wt[1], gb2[0], h1);
    // layer 2
    k_aggs<<<gagg, 512, 0, stream>>>(h1, t, rp, colv);
    k_mlp<<<gtile2, 512, 0, stream>>>(t, wt[2], gb1[1], wt[3], gb2[1], h2);
    // layer 3
    k_aggs<<<gagg, 512, 0, stream>>>(h2, t, rp, colv);
    k_mlp<<<gtile2, 512, 0, stream>>>(t, wt[4], gb1[2], wt[5], gb2[2], h3);
    // head
    k_final<<<gtile1, 512, 0, stream>>>(h1, h2, h3, l1t, l1b, l2t, l2b, out);
}